// Round 6
// baseline (241.375 us; speedup 1.0000x reference)
//
#include <hip/hip_runtime.h>

// TokenEmbedding segment-sum, MI355X. v6: grouped per-token streaming.
//
// History: block-per-token (v0/v4, ~72us seg) is latency-bound: each of
// 32768 tiny blocks pays {scalar boundary load -> ~1.3 row loads -> store}
// serially, ~2.8 TB/s vs the 6.8 TB/s the harness's own fill achieves.
// v5 (readlane-streaming) crashed on-device; its amortization idea is kept
// here WITHOUT tok[] access / readlane / divergent flush loops:
//
// One 256-thread block per GROUP=8 consecutive tokens (4096 blocks).
// tok is sorted, so the group's rows [start[t0], start[t0+8]) are
// contiguous and the 9 boundaries start[t0..t0+8] partition them.
//   - 9 wave-uniform boundary loads (scalar path), paid once per 8 tokens
//     (8x amortization vs v4);
//   - token loop fully unrolled: token j+1's row loads are data-independent
//     of token j's accumulate -> compiler can overlap loads across tokens
//     (multi-row flight depth, impossible in the per-token-block layout);
//   - inner run loop 2-row unrolled, two independent accumulators;
//   - nontemporal row stores (output never re-read);
//   - empty tokens store zeros (poisoned d_out handled, no memset pass).
//
//  Phase 1 (unchanged, known-good): boundary-scatter start[b][t], t in 0..L,
//  row stride LSTRIDE=L+8.

#define B_DIM 8
#define L_DIM 4096
#define H_DIM 1024
#define LSTRIDE (L_DIM + 8)   // start-table row stride (ints)
#define GROUP 8               // tokens per block
#define GPB (L_DIM / GROUP)   // groups per batch = 512

typedef float fx4 __attribute__((ext_vector_type(4)));

__global__ __launch_bounds__(256) void build_starts_kernel(
    const int* __restrict__ tok,   // [B, L] sorted per batch
    int* __restrict__ start)       // [B, LSTRIDE], entries 0..L valid
{
    const int gid = blockIdx.x * 256 + threadIdx.x;   // 0 .. B*L-1
    const int b = gid >> 12;
    const int w = gid & (L_DIM - 1);

    const int* __restrict__ row = tok + (size_t)b * L_DIM;
    const int cur  = row[w];
    const int prev = (w > 0) ? row[w - 1] : -1;

    int* __restrict__ srow = start + (size_t)b * LSTRIDE;
    for (int t = prev + 1; t <= cur; ++t) srow[t] = w;
    if (w == L_DIM - 1) {
        for (int t = cur + 1; t <= L_DIM; ++t) srow[t] = L_DIM;
    }
}

__global__ __launch_bounds__(256) void token_seg_sum_kernel(
    const float* __restrict__ seq,   // [B, L, H] fp32
    const int* __restrict__ start,   // [B, LSTRIDE]
    float* __restrict__ out)         // [B, L, H] fp32
{
    const int g  = blockIdx.x;            // 0 .. B*GPB-1
    const int b  = g / GPB;
    const int t0 = (g % GPB) * GROUP;     // first token of this group

    // 9 wave-uniform boundary loads -> scalar path, once per block.
    const int* __restrict__ srow = start + b * LSTRIDE + t0;
    int sb[GROUP + 1];
#pragma unroll
    for (int i = 0; i <= GROUP; ++i) sb[i] = srow[i];

    const int tid = threadIdx.x;          // one fx4 column slot per thread
    const fx4* __restrict__ base =
        (const fx4*)seq + ((size_t)b << 20) + tid;
    fx4* __restrict__ obase =
        (fx4*)out + (((size_t)(b << 12) + t0) << 8) + tid;

#pragma unroll
    for (int jj = 0; jj < GROUP; ++jj) {  // unrolled: loads of token jj+1
        const int s = sb[jj];             // are independent of token jj's
        const int e = sb[jj + 1];         // accumulate -> cross-token ILP
        fx4 a0 = (fx4)0.f;
        fx4 a1 = (fx4)0.f;
        int w = s;
        for (; w + 2 <= e; w += 2) {      // 2 independent loads in flight
            a0 += base[(size_t)w << 8];
            a1 += base[(size_t)(w + 1) << 8];
        }
        if (w < e) a0 += base[(size_t)w << 8];
        a0 += a1;
        __builtin_nontemporal_store(a0, obase + ((size_t)jj << 8));
    }
}

extern "C" void kernel_launch(void* const* d_in, const int* in_sizes, int n_in,
                              void* d_out, int out_size, void* d_ws, size_t ws_size,
                              hipStream_t stream) {
    const float* seq = (const float*)d_in[0];
    const int*   tok = (const int*)d_in[1];
    float*       out = (float*)d_out;
    int*         start = (int*)d_ws;            // B*LSTRIDE ints = 131.3 KB

    build_starts_kernel<<<dim3(B_DIM * L_DIM / 256), dim3(256), 0, stream>>>(tok, start);

    // One block per 8-token group: B*L/GROUP = 4096 blocks.
    token_seg_sum_kernel<<<dim3(B_DIM * GPB), dim3(256), 0, stream>>>(
        seq, start, out);
}

// Round 7
// 238.347 us; speedup vs baseline: 1.0127x; 1.0127x over previous
//
#include <hip/hip_runtime.h>

// TokenEmbedding segment-sum, MI355X. v7: input-slice streaming, no table.
//
// Post-mortem v0-v6: every gather variant (block-per-token 72us,
// wave-per-4-tokens 86us, block-per-8-tokens 85us) is latency-bound at
// 2.4-2.9 TB/s because row-load ADDRESSES depend on loaded boundary data:
// each wave pays {scalar load -> wait -> row loads -> wait} serially and
// never keeps the memory queues full. The harness fill hits 6.8 TB/s with
// addresses that are pure functions of thread id.
//
// v7 removes the dependence: one 256-thread block per 8 consecutive INPUT
// rows [r0, r0+8) (4096 blocks). The 8 row loads (8 KB/wave, 32 KB/block)
// issue unconditionally at wave start -- addresses derive from blockIdx
// only. Segmentation is resolved afterwards from tok[r0-1..r0+7] (scalar,
// wave-uniform):
//   - statically-unrolled walk over the 8 preloaded rows (static register
//     indices), accumulate, flush on token change with nt stores;
//   - ownership: a slice owns token t iff t's first row lies in the slice.
//     Runs crossing the slice end are finished with dynamic loads (~1 extra
//     row expected, Poisson(1) run lengths). Slices fully inside a longer
//     run skip (started flag). Empty tokens are zero-stored at the boundary
//     owning their insertion point; batch-trailing empties by the last
//     slice. Every output row written exactly once (poison-safe), no
//     atomics, no start table, no phase 1.

#define B_DIM 8
#define L_DIM 4096
#define H_DIM 1024
#define RPW 8                  // input rows per block
#define SPB (L_DIM / RPW)      // slices per batch = 512

typedef float fx4 __attribute__((ext_vector_type(4)));

__global__ __launch_bounds__(256) void token_seg_sum_kernel(
    const float* __restrict__ seq,   // [B, L, H] fp32
    const int* __restrict__ tok,     // [B, L] sorted per batch
    float* __restrict__ out)         // [B, L, H] fp32
{
    const int g  = blockIdx.x;            // 0 .. B*SPB-1
    const int b  = g / SPB;
    const int r0 = (g % SPB) * RPW;       // first input row of this slice

    const int tid = threadIdx.x;          // one fx4 column slot per thread
    const fx4* __restrict__ base = (const fx4*)seq + ((size_t)b << 20) + tid;
    fx4* __restrict__ obase      = (fx4*)out + ((size_t)b << 20) + tid;
    const int* __restrict__ trow = tok + ((size_t)b << 12);

    // Dependence-free: issue all 8 row loads immediately (addresses are
    // pure functions of blockIdx/threadIdx).
    fx4 row[RPW];
#pragma unroll
    for (int r = 0; r < RPW; ++r)
        row[r] = base[(size_t)(r0 + r) << 8];

    // Wave-uniform token ids for the slice (+ the row just before it).
    int tk[RPW];
#pragma unroll
    for (int r = 0; r < RPW; ++r) tk[r] = trow[r0 + r];
    const int jprev = (r0 == 0) ? -1 : trow[r0 - 1];

    fx4 acc = (fx4)0.f;
    int  prev    = jprev;   // token of the run currently tracked
    bool started = false;   // run began inside this slice -> we own it

#pragma unroll
    for (int r = 0; r < RPW; ++r) {
        const int t = tk[r];
        if (t != prev) {
            // flush the run we own (if any)
            if (started)
                __builtin_nontemporal_store(acc, obase + ((size_t)prev << 8));
            // empty tokens (prev, t): insertion point is row r0+r -> ours
            for (int j = prev + 1; j < t; ++j)
                __builtin_nontemporal_store((fx4)0.f, obase + ((size_t)j << 8));
            acc     = row[r];            // static register index
            prev    = t;
            started = true;
        } else if (started) {
            acc += row[r];               // static register index
        }
        // !started && t==prev: row belongs to the previous slice's run; skip
    }

    if (started) {
        // Run may continue past the slice: finish it (dynamic loads; rare,
        // run lengths are Poisson(1), max ~10).
        int w = r0 + RPW;
        while (w < L_DIM && trow[w] == prev) {
            acc += base[(size_t)w << 8];
            ++w;
        }
        __builtin_nontemporal_store(acc, obase + ((size_t)prev << 8));
    }

    // Last slice of the batch also owns trailing empty tokens.
    if (r0 + RPW == L_DIM) {
        const int tlast = tk[RPW - 1];
        for (int j = tlast + 1; j < L_DIM; ++j)
            __builtin_nontemporal_store((fx4)0.f, obase + ((size_t)j << 8));
    }
}

extern "C" void kernel_launch(void* const* d_in, const int* in_sizes, int n_in,
                              void* d_out, int out_size, void* d_ws, size_t ws_size,
                              hipStream_t stream) {
    const float* seq = (const float*)d_in[0];
    const int*   tok = (const int*)d_in[1];
    float*       out = (float*)d_out;
    (void)d_ws; (void)ws_size;

    // One block per 8-row input slice: B*L/RPW = 4096 blocks.
    token_seg_sum_kernel<<<dim3(B_DIM * SPB), dim3(256), 0, stream>>>(
        seq, tok, out);
}